// Round 7
// baseline (158.002 us; speedup 1.0000x reference)
//
#include <hip/hip_runtime.h>
#include <hip/hip_fp16.h>

#define NN 50000
#define NE 800000
#define D 64
#define K1BLK 1024      // 1024 x 512thr = 4 blocks/CU = full wave capacity
#define EPB 782         // 1024*782 = 800768 >= 800000 (guarded)
#define PPB 1563        // h float2-packs per block: 1024*1563 >= 1,600,000
#define SLOTS 48        // per-node slot cap; max in-degree ~37
#define SNODES 16       // nodes per K2 block; 3125*16 = 50000 exact
#define K2BLK 3125

typedef __attribute__((ext_vector_type(8))) short short8;
typedef __attribute__((ext_vector_type(4))) float f32x4;

static __device__ __forceinline__ unsigned rne_pack(float x, float y) {
    unsigned a = __float_as_uint(x), c = __float_as_uint(y);
    a += 0x7FFFu + ((a >> 16) & 1u);
    c += 0x7FFFu + ((c >> 16) & 1u);
    return (a >> 16) | (c & 0xFFFF0000u);
}

// ---------------------------------------------------------------------------
// K1: barrier-free.  Packs h (and W) to bf16, then scatters each edge record
// rec = (src<<16)|half(w) directly into its destination node's slot segment:
// gslot[dst*48 + atomicAdd(&gcnt[dst],1)].  Replaces the entire LDS
// hist/scan/stage/flush bucketizer (R6) — k2's phase A becomes a dense
// coalesced copy.  gcnt also serves as the degree array for the mean.
// Atomic contention trivial (<=37 per counter); gslot (9.6MB) is L2-resident.
// ---------------------------------------------------------------------------
__global__ __launch_bounds__(512) void k_scatter(const int* __restrict__ dst,
                                                 const int* __restrict__ src,
                                                 const float* __restrict__ w,
                                                 const float* __restrict__ h,
                                                 const float* __restrict__ W,
                                                 unsigned* __restrict__ hb,
                                                 unsigned* __restrict__ Wb,
                                                 int* __restrict__ gcnt,
                                                 unsigned* __restrict__ gslot)
{
    int tid = threadIdx.x;
    int blk = blockIdx.x;

    // ---- bf16 pack of h slice (batched loads for MLP); block 0 packs W ----
    {
        size_t base = (size_t)blk * PPB;
        float2 v[4];
        #pragma unroll
        for (int k = 0; k < 4; k++) {
            int i = tid + k * 512;
            if (i < PPB && base + i < (size_t)(NN * D / 2))
                v[k] = ((const float2*)h)[base + i];
        }
        #pragma unroll
        for (int k = 0; k < 4; k++) {
            int i = tid + k * 512;
            if (i < PPB && base + i < (size_t)(NN * D / 2))
                hb[base + i] = rne_pack(v[k].x, v[k].y);
        }
        if (blk == 0) {
            float2 vw[8];
            #pragma unroll
            for (int k = 0; k < 8; k++)
                vw[k] = ((const float2*)W)[tid + k * 512];   // 4096 exact
            #pragma unroll
            for (int k = 0; k < 8; k++)
                Wb[tid + k * 512] = rne_pack(vw[k].x, vw[k].y);
        }
    }

    // ---- per-node scatter (2-deep prefetch; no barriers) ----
    int ebase = blk * EPB;
    int dl[2], sl[2];
    float wl[2];
    #pragma unroll
    for (int k = 0; k < 2; k++) {
        int i = tid + k * 512;
        int e = ebase + i;
        bool vld = (i < EPB) && (e < NE);
        dl[k] = vld ? dst[e] : -1;
        sl[k] = vld ? src[e] : 0;
        wl[k] = vld ? w[e] : 0.f;
    }
    #pragma unroll
    for (int k = 0; k < 2; k++) {
        if (dl[k] >= 0) {
            unsigned rec = ((unsigned)sl[k] << 16) |
                           (unsigned)__half_as_ushort(__float2half(wl[k]));
            int pos = atomicAdd(&gcnt[dl[k]], 1);
            if (pos < SLOTS) gslot[(size_t)dl[k] * SLOTS + pos] = rec;
        }
    }
}

// ---------------------------------------------------------------------------
// K2: fused bin + aggregate + MFMA GEMM.  256 thr, 16 nodes, 3125 blocks
// exact (12.2x oversubscription, 8 blocks/CU).  Phase A is now THREE
// unconditional coalesced 1KB loads (slot segments are contiguous per node:
// gslot + nbase*48 + idx) + one 64B deg read.  Garbage slots beyond deg[n]
// are never consumed (phase B guards with `valid`).  One barrier before B.
// Phases B/C proven (R0/R6); invariant loads hoisted to kernel top.
// ---------------------------------------------------------------------------
__global__ __launch_bounds__(256) void k_fused(const unsigned* __restrict__ hb,
                                               const int* __restrict__ gcnt,
                                               const unsigned* __restrict__ gslot,
                                               const unsigned* __restrict__ Wb,
                                               const float* __restrict__ b,
                                               float* __restrict__ out)
{
    __shared__ unsigned slots[SNODES * SLOTS];                 // 3072B
    __shared__ __align__(16) unsigned short hNl[SNODES * 72];  // 2304B
    __shared__ int deg[SNODES];

    int tid  = threadIdx.x;
    int lane = tid & 63;
    int wv   = __builtin_amdgcn_readfirstlane(tid >> 6);
    int nbase = blockIdx.x * SNODES;        // 3125*16 = 50000 exact, no tail

    int m    = lane & 15;                   // node row within tile / B col
    int quad = lane >> 4;
    int j    = wv * 16 + m;                 // out feature owned by this lane
    int ng   = nbase + m;

    // hoisted loop-invariant loads (issued first; consumed in phase C)
    short8 bf[4];
    #pragma unroll
    for (int kk = 0; kk < 4; kk++) {
        uint4 bw = *(const uint4*)(Wb + (size_t)j * 64 + kk * 16 + quad * 4);
        bf[kk] = *(short8*)&bw;
    }
    float bv = b[j];
    uint4 t0 = *(const uint4*)(hb + (size_t)ng * 32 + 0 * 16 + quad * 4);
    uint4 t1 = *(const uint4*)(hb + (size_t)ng * 32 + 1 * 16 + quad * 4);

    // ---- phase A: dense coalesced slot copy + deg read ----
    {
        const unsigned* gsl = gslot + (size_t)nbase * SLOTS;   // 768 words
        unsigned c0 = gsl[tid];
        unsigned c1 = gsl[tid + 256];
        unsigned c2 = gsl[tid + 512];
        if (tid < SNODES) deg[tid] = gcnt[nbase + tid];
        slots[tid]       = c0;
        slots[tid + 256] = c1;
        slots[tid + 512] = c2;
    }
    __syncthreads();

    // ---- phase B: aggregate (4 waves x 4 nodes; lane = g*16+q) ----
    int g = lane >> 4, q = lane & 15;
    #pragma unroll 2
    for (int mm2 = 0; mm2 < 4; mm2++) {
        int local = wv * 4 + mm2;
        int dg = deg[local];
        int mm = min(dg, SLOTS);
        const unsigned* sl = &slots[local * SLOTS];
        float4 acc = make_float4(0.f, 0.f, 0.f, 0.f);
        #pragma unroll 1
        for (int cb = 0; cb < mm; cb += 16) {
            #pragma unroll
            for (int jj = 0; jj < 4; jj++) {
                int ii = cb + jj * 4 + g;   // <= 47 < SLOTS always
                bool valid = ii < mm;
                unsigned rec = sl[ii];
                float wv2 = valid
                    ? __half2float(__ushort_as_half(
                          (unsigned short)(rec & 0xFFFFu)))
                    : 0.f;
                int s = valid ? (int)(rec >> 16) : 0;
                uint2 hv = *(const uint2*)(hb + (size_t)s * 32 + q * 2);
                acc.x += wv2 * __uint_as_float(hv.x << 16);
                acc.y += wv2 * __uint_as_float(hv.x & 0xFFFF0000u);
                acc.z += wv2 * __uint_as_float(hv.y << 16);
                acc.w += wv2 * __uint_as_float(hv.y & 0xFFFF0000u);
            }
        }
        acc.x += __shfl_xor(acc.x, 16); acc.y += __shfl_xor(acc.y, 16);
        acc.z += __shfl_xor(acc.z, 16); acc.w += __shfl_xor(acc.w, 16);
        acc.x += __shfl_xor(acc.x, 32); acc.y += __shfl_xor(acc.y, 32);
        acc.z += __shfl_xor(acc.z, 32); acc.w += __shfl_xor(acc.w, 32);
        if (g == 0) {
            float inv = 1.0f / fmaxf((float)dg, 1.0f);
            uint2 o;
            o.x = rne_pack(acc.x * inv, acc.y * inv);
            o.y = rne_pack(acc.z * inv, acc.w * inv);
            *(uint2*)&hNl[local * 72 + q * 4] = o;
        }
    }
    __syncthreads();

    // ---- phase C: MFMA GEMM; all waves share A-rows, wave = 16 out-feats --
    {
        short8 a[4];
        {
            uint4 t2 = *(const uint4*)&hNl[m * 72 + 0 * 32 + quad * 8];
            uint4 t3 = *(const uint4*)&hNl[m * 72 + 1 * 32 + quad * 8];
            a[0] = *(short8*)&t0; a[1] = *(short8*)&t1;
            a[2] = *(short8*)&t2; a[3] = *(short8*)&t3;
        }

        f32x4 acc = {bv, bv, bv, bv};
        #pragma unroll
        for (int kk = 0; kk < 4; kk++)
            acc = __builtin_amdgcn_mfma_f32_16x16x32_bf16(a[kk], bf[kk],
                                                          acc, 0, 0, 0);
        #pragma unroll
        for (int r = 0; r < 4; r++) {
            int lrow = quad * 4 + r;        // D: col=lane&15, row=quad*4+r
            out[(size_t)(nbase + lrow) * 64 + j] = acc[r];
        }
    }
}

extern "C" void kernel_launch(void* const* d_in, const int* in_sizes, int n_in,
                              void* d_out, int out_size, void* d_ws, size_t ws_size,
                              hipStream_t stream) {
    const float* h   = (const float*)d_in[0];
    const float* w   = (const float*)d_in[1];
    const int*   src = (const int*)d_in[2];
    const int*   dst = (const int*)d_in[3];
    const float* W   = (const float*)d_in[4];
    const float* b   = (const float*)d_in[5];
    float* out = (float*)d_out;

    // workspace: hb 6.4MB + Wb 16KB + gcnt 200KB + gslot 9.6MB = ~16.2MB
    char* p = (char*)d_ws;
    unsigned* hb    = (unsigned*)p;  p += (size_t)(NN * D / 2) * 4;
    unsigned* Wb    = (unsigned*)p;  p += (size_t)(64 * 128 / 2) * 4;
    int* gcnt       = (int*)p;       p += (size_t)NN * 4;
    unsigned* gslot = (unsigned*)p;  // NN * SLOTS * 4 = 9,600,000 bytes

    hipMemsetAsync(gcnt, 0, (size_t)NN * 4, stream);

    k_scatter<<<K1BLK, 512, 0, stream>>>(dst, src, w, h, W, hb, Wb,
                                         gcnt, gslot);

    k_fused <<<K2BLK, 256, 0, stream>>>(hb, gcnt, gslot, Wb, b, out);
}

// Round 8
// 121.878 us; speedup vs baseline: 1.2964x; 1.2964x over previous
//
#include <hip/hip_runtime.h>
#include <hip/hip_fp16.h>

#define NN 50000
#define NE 800000
#define D 64
#define K1BLK 512       // k_bucket grid (k2 walk length depends on this)
#define K1THR 1024      // 512 blk x 1024 thr = 2 blk/CU x 16 waves = 32/32 waves
#define EPB 1563        // edges per k1 block (512*1563 = 800256 >= 800000)
#define REG 1568        // per-block region stride in records (uint4 flush pad)
#define NSB 2048        // sub-buckets (dst>>5): 1563 used, padded to 2048
#define SNODES 16       // nodes per K2 block; 3125*16 = 50000 exact, no tail
#define SLOTS 48        // per-node slot cap; max deg ~37
#define K2BLK 3125

typedef __attribute__((ext_vector_type(8))) short short8;
typedef __attribute__((ext_vector_type(4))) float f32x4;

static __device__ __forceinline__ unsigned rne_pack(float x, float y) {
    unsigned a = __float_as_uint(x), c = __float_as_uint(y);
    a += 0x7FFFu + ((a >> 16) & 1u);
    c += 0x7FFFu + ((c >> 16) & 1u);
    return (a >> 16) | (c & 0xFFFF0000u);
}

// ---------------------------------------------------------------------------
// K1: bucketize at 32-node granularity (sbkt = dst>>5) + folded bf16 pack.
// R6 logic, but 1024 threads/block: grid 512 x 1024 = full 32-wave occupancy
// per CU (R6 ran at 16/32 waves and every k1 probe showed latency-bound
// signatures).  Deterministic layout, no global atomics, no memset node.
// Directory row-major, one coalesced uint2 store per thread.
// ---------------------------------------------------------------------------
__global__ __launch_bounds__(K1THR) void k_bucket(const int* __restrict__ dst,
                                                  const int* __restrict__ src,
                                                  const float* __restrict__ w,
                                                  const float* __restrict__ h,
                                                  const float* __restrict__ W,
                                                  unsigned* __restrict__ hb,
                                                  unsigned* __restrict__ Wb,
                                                  unsigned* __restrict__ gidx,
                                                  uint2* __restrict__ gsegB)
{
    __shared__ int hist[NSB], cur[NSB];
    __shared__ int wsum[16];
    __shared__ uint2 stage[REG];
    int tid  = threadIdx.x;             // 0..1023
    int blk  = blockIdx.x;
    int lane = tid & 63;
    int wid  = tid >> 6;                // 0..15

    // folded prep: pack h slice (and W once) to bf16, batched loads for MLP
    {
        int base = blk * 3125;                  // 512*3125 = 1,600,000 exact
        float2 v[4];
        #pragma unroll
        for (int k = 0; k < 4; k++) {
            int i = tid + k * 1024;
            if (i < 3125) v[k] = ((const float2*)h)[base + i];
        }
        #pragma unroll
        for (int k = 0; k < 4; k++) {
            int i = tid + k * 1024;
            if (i < 3125) hb[base + i] = rne_pack(v[k].x, v[k].y);
        }
        if (blk == 0) {
            float2 vw[4];
            #pragma unroll
            for (int k = 0; k < 4; k++)
                vw[k] = ((const float2*)W)[tid + k * 1024];  // 4096 exact
            #pragma unroll
            for (int k = 0; k < 4; k++)
                Wb[tid + k * 1024] = rne_pack(vw[k].x, vw[k].y);
        }
    }

    int ebase = blk * EPB;
    int epbv = NE - ebase; if (epbv > EPB) epbv = EPB;

    hist[tid] = 0; hist[tid + 1024] = 0;
    __syncthreads();

    // prefetch dst + src + w 2-deep (latency hides under hist+scan)
    int dloc[2], sloc[2];
    float wloc[2];
    #pragma unroll
    for (int k = 0; k < 2; k++) {
        int i = tid + k * 1024;
        bool vld = i < epbv;
        dloc[k] = vld ? dst[ebase + i] : -1;
        sloc[k] = vld ? src[ebase + i] : 0;
        wloc[k] = vld ? w[ebase + i] : 0.f;
    }
    #pragma unroll
    for (int k = 0; k < 2; k++)
        if (dloc[k] >= 0) atomicAdd(&hist[dloc[k] >> 5], 1);
    __syncthreads();

    // exclusive scan of hist[2048]: 2 consecutive entries per thread,
    // wave shuffle scan of thread sums, block scan of 16 wave sums
    int b0 = hist[2 * tid], b1 = hist[2 * tid + 1];
    int ts = b0 + b1;
    int v = ts;
    #pragma unroll
    for (int dd = 1; dd < 64; dd <<= 1) {
        int t = __shfl_up(v, dd);
        if (lane >= dd) v += t;
    }
    if (lane == 63) wsum[wid] = v;
    __syncthreads();
    if (tid < 64) {
        int s = (tid < 16) ? wsum[tid] : 0;
        #pragma unroll
        for (int dd = 1; dd < 16; dd <<= 1) {
            int t = __shfl_up(s, dd);
            if (tid >= dd) s += t;
        }
        if (tid < 16) wsum[tid] = s;
    }
    __syncthreads();
    int base0 = v - ts + ((wid > 0) ? wsum[wid - 1] : 0);
    int base1 = base0 + b0;
    cur[2 * tid] = base0; cur[2 * tid + 1] = base1;
    // ROW-MAJOR directory: one coalesced uint2 store per thread
    ((uint2*)(gidx + (size_t)blk * NSB))[tid] =
        make_uint2((unsigned)base0 | ((unsigned)b0 << 16),
                   (unsigned)base1 | ((unsigned)b1 << 16));
    __syncthreads();

    // placement into dense LDS stage (all operands from registers)
    #pragma unroll
    for (int k = 0; k < 2; k++) {
        if (dloc[k] >= 0) {
            int d = dloc[k];
            unsigned rec = ((unsigned)sloc[k] << 16) |
                           (unsigned)__half_as_ushort(__float2half(wloc[k]));
            int pos = atomicAdd(&cur[d >> 5], 1);
            stage[pos] = make_uint2(rec, (unsigned)(d & 31));
        }
    }
    __syncthreads();

    // dense coalesced flush: 784 uint4 stores, one per thread (tid < 784)
    {
        uint4* dstq = (uint4*)(gsegB + (size_t)blk * REG);
        const uint4* srcq = (const uint4*)stage;
        if (tid < REG / 2) dstq[tid] = srcq[tid];
    }
}

// ---------------------------------------------------------------------------
// K2: fused bin + aggregate + MFMA GEMM.  256 thr, 16 nodes, 3125 blocks
// exact (12.2x oversubscription).  R6 logic + __launch_bounds__(256, 8):
// pins VGPR <= 64 so the hoisted bf[]/t0/t1 can't silently halve resident
// waves (8 blocks/CU = 32 waves/CU guaranteed).
// ---------------------------------------------------------------------------
__global__ __launch_bounds__(256, 8) void k_fused(const unsigned* __restrict__ hb,
                                                  const unsigned* __restrict__ gidx,
                                                  const uint2* __restrict__ gsegB,
                                                  const unsigned* __restrict__ Wb,
                                                  const float* __restrict__ b,
                                                  float* __restrict__ out)
{
    __shared__ unsigned slots[SNODES * SLOTS];                 // 3072B
    __shared__ __align__(16) unsigned short hNl[SNODES * 72];  // 2304B
    __shared__ int deg[SNODES];

    int tid  = threadIdx.x;
    int lane = tid & 63;
    int wv   = __builtin_amdgcn_readfirstlane(tid >> 6);
    int nbase = blockIdx.x * SNODES;        // 3125*16 = 50000 exact, no tail
    int sb    = nbase >> 5;                 // sub-bucket (32 nodes)
    unsigned lo = (unsigned)(nbase & 31);   // 0 or 16

    int m    = lane & 15;                   // node row within tile / B col
    int quad = lane >> 4;
    int j    = wv * 16 + m;                 // out feature owned by this lane
    int ng   = nbase + m;

    // hoisted loop-invariant loads (issue before phase A; no later stall)
    short8 bf[4];
    #pragma unroll
    for (int kk = 0; kk < 4; kk++) {
        uint4 bw = *(const uint4*)(Wb + (size_t)j * 64 + kk * 16 + quad * 4);
        bf[kk] = *(short8*)&bw;
    }
    float bv = b[j];
    uint4 t0 = *(const uint4*)(hb + (size_t)ng * 32 + 0 * 16 + quad * 4);
    uint4 t1 = *(const uint4*)(hb + (size_t)ng * 32 + 1 * 16 + quad * 4);

    // strided directory reads (row-major gidx), issued before deg init
    unsigned e0 = gidx[(size_t)(2 * tid)     * NSB + sb];
    unsigned e1 = gidx[(size_t)(2 * tid + 1) * NSB + sb];

    if (tid < SNODES) deg[tid] = 0;
    __syncthreads();

    // ---- phase A: walk 512 lambda~1 runs, 2 interleaved per thread ----
    {
        int c0 = (int)(e0 >> 16), c1 = (int)(e1 >> 16);
        const uint2* r0 = gsegB + (size_t)(2 * tid)     * REG + (e0 & 0xFFFFu);
        const uint2* r1 = gsegB + (size_t)(2 * tid + 1) * REG + (e1 & 0xFFFFu);
        int n = max(c0, c1);
        for (int k = 0; k < n; k++) {
            uint2 a, c;
            bool va = k < c0, vb = k < c1;
            if (va) a = r0[k];
            if (vb) c = r1[k];
            if (va) {
                unsigned ll = a.y - lo;
                if (ll < (unsigned)SNODES) {
                    int p = atomicAdd(&deg[ll], 1);
                    if (p < SLOTS) slots[ll * SLOTS + p] = a.x;
                }
            }
            if (vb) {
                unsigned ll = c.y - lo;
                if (ll < (unsigned)SNODES) {
                    int p = atomicAdd(&deg[ll], 1);
                    if (p < SLOTS) slots[ll * SLOTS + p] = c.x;
                }
            }
        }
    }
    __syncthreads();

    // ---- phase B: aggregate (4 waves x 4 nodes; lane = g*16+q) ----
    int g = lane >> 4, q = lane & 15;
    #pragma unroll 2
    for (int mm2 = 0; mm2 < 4; mm2++) {
        int local = wv * 4 + mm2;
        int dg = deg[local];
        int mm = min(dg, SLOTS);
        const unsigned* sl = &slots[local * SLOTS];
        float4 acc = make_float4(0.f, 0.f, 0.f, 0.f);
        #pragma unroll 1
        for (int cb = 0; cb < mm; cb += 16) {
            #pragma unroll
            for (int jj = 0; jj < 4; jj++) {
                int ii = cb + jj * 4 + g;   // <= 47 < SLOTS always
                bool valid = ii < mm;
                unsigned rec = sl[ii];
                float wv2 = valid
                    ? __half2float(__ushort_as_half(
                          (unsigned short)(rec & 0xFFFFu)))
                    : 0.f;
                int s = valid ? (int)(rec >> 16) : 0;
                uint2 hv = *(const uint2*)(hb + (size_t)s * 32 + q * 2);
                acc.x += wv2 * __uint_as_float(hv.x << 16);
                acc.y += wv2 * __uint_as_float(hv.x & 0xFFFF0000u);
                acc.z += wv2 * __uint_as_float(hv.y << 16);
                acc.w += wv2 * __uint_as_float(hv.y & 0xFFFF0000u);
            }
        }
        acc.x += __shfl_xor(acc.x, 16); acc.y += __shfl_xor(acc.y, 16);
        acc.z += __shfl_xor(acc.z, 16); acc.w += __shfl_xor(acc.w, 16);
        acc.x += __shfl_xor(acc.x, 32); acc.y += __shfl_xor(acc.y, 32);
        acc.z += __shfl_xor(acc.z, 32); acc.w += __shfl_xor(acc.w, 32);
        if (g == 0) {
            float inv = 1.0f / fmaxf((float)dg, 1.0f);
            uint2 o;
            o.x = rne_pack(acc.x * inv, acc.y * inv);
            o.y = rne_pack(acc.z * inv, acc.w * inv);
            *(uint2*)&hNl[local * 72 + q * 4] = o;
        }
    }
    __syncthreads();

    // ---- phase C: MFMA GEMM; all waves share A-rows, wave = 16 out-feats --
    {
        short8 a[4];
        {
            uint4 t2 = *(const uint4*)&hNl[m * 72 + 0 * 32 + quad * 8];
            uint4 t3 = *(const uint4*)&hNl[m * 72 + 1 * 32 + quad * 8];
            a[0] = *(short8*)&t0; a[1] = *(short8*)&t1;
            a[2] = *(short8*)&t2; a[3] = *(short8*)&t3;
        }

        f32x4 acc = {bv, bv, bv, bv};
        #pragma unroll
        for (int kk = 0; kk < 4; kk++)
            acc = __builtin_amdgcn_mfma_f32_16x16x32_bf16(a[kk], bf[kk],
                                                          acc, 0, 0, 0);
        #pragma unroll
        for (int r = 0; r < 4; r++) {
            int lrow = quad * 4 + r;        // D: col=lane&15, row=quad*4+r
            out[(size_t)(nbase + lrow) * 64 + j] = acc[r];
        }
    }
}

extern "C" void kernel_launch(void* const* d_in, const int* in_sizes, int n_in,
                              void* d_out, int out_size, void* d_ws, size_t ws_size,
                              hipStream_t stream) {
    const float* h   = (const float*)d_in[0];
    const float* w   = (const float*)d_in[1];
    const int*   src = (const int*)d_in[2];
    const int*   dst = (const int*)d_in[3];
    const float* W   = (const float*)d_in[4];
    const float* b   = (const float*)d_in[5];
    float* out = (float*)d_out;

    // workspace: hb 6.4MB + Wb 16KB + gidx 4MB + gsegB 6.4MB = ~16.9MB
    char* p = (char*)d_ws;
    unsigned* hb   = (unsigned*)p;  p += (size_t)(NN * D / 2) * 4;
    unsigned* Wb   = (unsigned*)p;  p += (size_t)(64 * 128 / 2) * 4;
    unsigned* gidx = (unsigned*)p;  p += (size_t)K1BLK * NSB * 4;
    uint2* gsegB   = (uint2*)p;     // K1BLK * REG * 8 = 6,422,528 bytes

    k_bucket<<<K1BLK, K1THR, 0, stream>>>(dst, src, w, h, W, hb, Wb,
                                          gidx, gsegB);

    k_fused <<<K2BLK, 256, 0, stream>>>(hb, gidx, gsegB, Wb, b, out);
}

// Round 9
// 118.575 us; speedup vs baseline: 1.3325x; 1.0279x over previous
//
#include <hip/hip_runtime.h>
#include <hip/hip_fp16.h>

#define NN 50000
#define NE 800000
#define D 64
#define K1BLK 512       // k_bucket grid (k2 walk length depends on this)
#define EPB 1563        // edges per k1 block (512*1563 = 800256 >= 800000)
#define REG 1568        // per-block region stride in records (64B-aligned)
#define NSB 4096        // sub-buckets (dst>>4): 3125 used, padded to 4096
#define SNODES 16       // nodes per K2 block == sub-bucket size (100% keep)
#define SLOTS 48        // per-node slot cap; max in-degree ~37
#define K2BLK 3125      // one block per sub-bucket; 3125*16 = 50000 exact

typedef __attribute__((ext_vector_type(8))) short short8;
typedef __attribute__((ext_vector_type(4))) float f32x4;

static __device__ __forceinline__ unsigned rne_pack(float x, float y) {
    unsigned a = __float_as_uint(x), c = __float_as_uint(y);
    a += 0x7FFFu + ((a >> 16) & 1u);
    c += 0x7FFFu + ((c >> 16) & 1u);
    return (a >> 16) | (c & 0xFFFF0000u);
}

// ---------------------------------------------------------------------------
// K1: bucketize at 16-node granularity (sbkt = dst>>4) + folded bf16 pack.
// R9 changes vs R6: (a) records stored DIRECTLY to the block-private global
// region (no LDS stage, no flush pass, one fewer barrier; region is single-
// XCD so L2 merges the scatter — unlike R7's cross-XCD per-node scatter);
// (b) directory entries built in registers during the scan (thread owns 8
// consecutive sub-buckets) and written as two coalesced uint4 stores.
// ---------------------------------------------------------------------------
__global__ __launch_bounds__(512) void k_bucket(const int* __restrict__ dst,
                                                const int* __restrict__ src,
                                                const float* __restrict__ w,
                                                const float* __restrict__ h,
                                                const float* __restrict__ W,
                                                unsigned* __restrict__ hb,
                                                unsigned* __restrict__ Wb,
                                                unsigned* __restrict__ gidx,
                                                uint2* __restrict__ gsegB)
{
    __shared__ int hist[NSB], cur[NSB];     // 32KB
    __shared__ int wsum[8];
    int tid  = threadIdx.x;
    int blk  = blockIdx.x;
    int lane = tid & 63;
    int wid  = tid >> 6;

    // folded prep: pack h slice (and W once) to bf16, batched loads for MLP
    {
        int base = blk * 3125;                  // 512*3125 = 1,600,000 exact
        float2 v[7];
        #pragma unroll
        for (int k = 0; k < 7; k++) {
            int i = tid + k * 512;
            if (i < 3125) v[k] = ((const float2*)h)[base + i];
        }
        #pragma unroll
        for (int k = 0; k < 7; k++) {
            int i = tid + k * 512;
            if (i < 3125) hb[base + i] = rne_pack(v[k].x, v[k].y);
        }
        if (blk == 0) {
            float2 vw[8];
            #pragma unroll
            for (int k = 0; k < 8; k++)
                vw[k] = ((const float2*)W)[tid + k * 512];   // 4096 exact
            #pragma unroll
            for (int k = 0; k < 8; k++)
                Wb[tid + k * 512] = rne_pack(vw[k].x, vw[k].y);
        }
    }

    int ebase = blk * EPB;
    int epbv = NE - ebase; if (epbv > EPB) epbv = EPB;

    #pragma unroll
    for (int k = 0; k < 8; k++) hist[tid + k * 512] = 0;
    __syncthreads();

    // prefetch dst + src + w 4-deep (latency hides under hist+scan)
    int dloc[4], sloc[4];
    float wloc[4];
    #pragma unroll
    for (int k = 0; k < 4; k++) {
        int i = tid + k * 512;
        bool vld = i < epbv;
        dloc[k] = vld ? dst[ebase + i] : -1;
        sloc[k] = vld ? src[ebase + i] : 0;
        wloc[k] = vld ? w[ebase + i] : 0.f;
    }
    #pragma unroll
    for (int k = 0; k < 4; k++)
        if (dloc[k] >= 0) atomicAdd(&hist[dloc[k] >> 4], 1);
    __syncthreads();

    // exclusive scan of hist[4096]: thread owns 8 CONSECUTIVE sub-buckets;
    // wave shuffle scan of thread sums, block scan of 8 wave sums
    int b[8], ts = 0;
    #pragma unroll
    for (int k = 0; k < 8; k++) { b[k] = hist[8 * tid + k]; ts += b[k]; }
    int v = ts;
    #pragma unroll
    for (int dd = 1; dd < 64; dd <<= 1) {
        int t = __shfl_up(v, dd);
        if (lane >= dd) v += t;
    }
    if (lane == 63) wsum[wid] = v;
    __syncthreads();
    if (tid < 64) {
        int s = (tid < 8) ? wsum[tid] : 0;
        #pragma unroll
        for (int dd = 1; dd < 8; dd <<= 1) {
            int t = __shfl_up(s, dd);
            if (tid >= dd) s += t;
        }
        if (tid < 8) wsum[tid] = s;
    }
    __syncthreads();
    {
        int base = v - ts + ((wid > 0) ? wsum[wid - 1] : 0);
        unsigned ent[8];
        #pragma unroll
        for (int k = 0; k < 8; k++) {
            cur[8 * tid + k] = base;
            ent[k] = (unsigned)base | ((unsigned)b[k] << 16);
            base += b[k];
        }
        // directory: two coalesced uint4 stores per thread (32B contiguous)
        uint4* gq = (uint4*)(gidx + (size_t)blk * NSB + 8 * tid);
        gq[0] = make_uint4(ent[0], ent[1], ent[2], ent[3]);
        gq[1] = make_uint4(ent[4], ent[5], ent[6], ent[7]);
    }
    __syncthreads();

    // placement DIRECT to block-private global region (no stage, no flush)
    uint2* regn = gsegB + (size_t)blk * REG;
    #pragma unroll
    for (int k = 0; k < 4; k++) {
        if (dloc[k] >= 0) {
            int d = dloc[k];
            unsigned rec = ((unsigned)sloc[k] << 16) |
                           (unsigned)__half_as_ushort(__float2half(wloc[k]));
            int pos = atomicAdd(&cur[d >> 4], 1);
            regn[pos] = make_uint2(rec, (unsigned)(d & 15));
        }
    }
}

// ---------------------------------------------------------------------------
// K2: fused bin + aggregate + MFMA GEMM.  256 thr, 16 nodes, 3125 blocks
// exact (12.2x oversubscription, 8 blocks/CU).  R9: sub-bucket == block's
// node set -> 100% keep rate, no range filter; phase A walks 800K records
// total (was 1.6M) and fetches ~39MB (was ~64MB).  Phases B/C proven (R6).
// ---------------------------------------------------------------------------
__global__ __launch_bounds__(256) void k_fused(const unsigned* __restrict__ hb,
                                               const unsigned* __restrict__ gidx,
                                               const uint2* __restrict__ gsegB,
                                               const unsigned* __restrict__ Wb,
                                               const float* __restrict__ b,
                                               float* __restrict__ out)
{
    __shared__ unsigned slots[SNODES * SLOTS];                 // 3072B
    __shared__ __align__(16) unsigned short hNl[SNODES * 72];  // 2304B
    __shared__ int deg[SNODES];

    int tid  = threadIdx.x;
    int lane = tid & 63;
    int wv   = __builtin_amdgcn_readfirstlane(tid >> 6);
    int nbase = blockIdx.x * SNODES;        // 3125*16 = 50000 exact, no tail
    int sb    = blockIdx.x;                 // sub-bucket == block (1:1)

    int m    = lane & 15;                   // node row within tile / B col
    int quad = lane >> 4;
    int j    = wv * 16 + m;                 // out feature owned by this lane
    int ng   = nbase + m;

    // hoisted loop-invariant loads (issue before phase A; no later stall)
    short8 bf[4];
    #pragma unroll
    for (int kk = 0; kk < 4; kk++) {
        uint4 bw = *(const uint4*)(Wb + (size_t)j * 64 + kk * 16 + quad * 4);
        bf[kk] = *(short8*)&bw;
    }
    float bv = b[j];
    uint4 t0 = *(const uint4*)(hb + (size_t)ng * 32 + 0 * 16 + quad * 4);
    uint4 t1 = *(const uint4*)(hb + (size_t)ng * 32 + 1 * 16 + quad * 4);

    // strided directory reads (row-major gidx), issued before deg init
    unsigned e0 = gidx[(size_t)(2 * tid)     * NSB + sb];
    unsigned e1 = gidx[(size_t)(2 * tid + 1) * NSB + sb];

    if (tid < SNODES) deg[tid] = 0;
    __syncthreads();

    // ---- phase A: walk 512 lambda~0.5 runs, 2/thread, no filter ----
    {
        int c0 = (int)(e0 >> 16), c1 = (int)(e1 >> 16);
        const uint2* r0 = gsegB + (size_t)(2 * tid)     * REG + (e0 & 0xFFFFu);
        const uint2* r1 = gsegB + (size_t)(2 * tid + 1) * REG + (e1 & 0xFFFFu);
        int n = max(c0, c1);
        for (int k = 0; k < n; k++) {
            uint2 a, c;
            bool va = k < c0, vb = k < c1;
            if (va) a = r0[k];
            if (vb) c = r1[k];
            if (va) {
                int p = atomicAdd(&deg[a.y], 1);
                if (p < SLOTS) slots[a.y * SLOTS + p] = a.x;
            }
            if (vb) {
                int p = atomicAdd(&deg[c.y], 1);
                if (p < SLOTS) slots[c.y * SLOTS + p] = c.x;
            }
        }
    }
    __syncthreads();

    // ---- phase B: aggregate (4 waves x 4 nodes; lane = g*16+q) ----
    int g = lane >> 4, q = lane & 15;
    #pragma unroll 2
    for (int mm2 = 0; mm2 < 4; mm2++) {
        int local = wv * 4 + mm2;
        int dg = deg[local];
        int mm = min(dg, SLOTS);
        const unsigned* sl = &slots[local * SLOTS];
        float4 acc = make_float4(0.f, 0.f, 0.f, 0.f);
        #pragma unroll 1
        for (int cb = 0; cb < mm; cb += 16) {
            #pragma unroll
            for (int jj = 0; jj < 4; jj++) {
                int ii = cb + jj * 4 + g;   // <= 47 < SLOTS always
                bool valid = ii < mm;
                unsigned rec = sl[ii];
                float wv2 = valid
                    ? __half2float(__ushort_as_half(
                          (unsigned short)(rec & 0xFFFFu)))
                    : 0.f;
                int s = valid ? (int)(rec >> 16) : 0;
                uint2 hv = *(const uint2*)(hb + (size_t)s * 32 + q * 2);
                acc.x += wv2 * __uint_as_float(hv.x << 16);
                acc.y += wv2 * __uint_as_float(hv.x & 0xFFFF0000u);
                acc.z += wv2 * __uint_as_float(hv.y << 16);
                acc.w += wv2 * __uint_as_float(hv.y & 0xFFFF0000u);
            }
        }
        acc.x += __shfl_xor(acc.x, 16); acc.y += __shfl_xor(acc.y, 16);
        acc.z += __shfl_xor(acc.z, 16); acc.w += __shfl_xor(acc.w, 16);
        acc.x += __shfl_xor(acc.x, 32); acc.y += __shfl_xor(acc.y, 32);
        acc.z += __shfl_xor(acc.z, 32); acc.w += __shfl_xor(acc.w, 32);
        if (g == 0) {
            float inv = 1.0f / fmaxf((float)dg, 1.0f);
            uint2 o;
            o.x = rne_pack(acc.x * inv, acc.y * inv);
            o.y = rne_pack(acc.z * inv, acc.w * inv);
            *(uint2*)&hNl[local * 72 + q * 4] = o;
        }
    }
    __syncthreads();

    // ---- phase C: MFMA GEMM; all waves share A-rows, wave = 16 out-feats --
    {
        short8 a[4];
        {
            uint4 t2 = *(const uint4*)&hNl[m * 72 + 0 * 32 + quad * 8];
            uint4 t3 = *(const uint4*)&hNl[m * 72 + 1 * 32 + quad * 8];
            a[0] = *(short8*)&t0; a[1] = *(short8*)&t1;
            a[2] = *(short8*)&t2; a[3] = *(short8*)&t3;
        }

        f32x4 acc = {bv, bv, bv, bv};
        #pragma unroll
        for (int kk = 0; kk < 4; kk++)
            acc = __builtin_amdgcn_mfma_f32_16x16x32_bf16(a[kk], bf[kk],
                                                          acc, 0, 0, 0);
        #pragma unroll
        for (int r = 0; r < 4; r++) {
            int lrow = quad * 4 + r;        // D: col=lane&15, row=quad*4+r
            out[(size_t)(nbase + lrow) * 64 + j] = acc[r];
        }
    }
}

extern "C" void kernel_launch(void* const* d_in, const int* in_sizes, int n_in,
                              void* d_out, int out_size, void* d_ws, size_t ws_size,
                              hipStream_t stream) {
    const float* h   = (const float*)d_in[0];
    const float* w   = (const float*)d_in[1];
    const int*   src = (const int*)d_in[2];
    const int*   dst = (const int*)d_in[3];
    const float* W   = (const float*)d_in[4];
    const float* b   = (const float*)d_in[5];
    float* out = (float*)d_out;

    // workspace: hb 6.4MB + Wb 16KB + gidx 8MB + gsegB 6.4MB = ~20.9MB
    char* p = (char*)d_ws;
    unsigned* hb   = (unsigned*)p;  p += (size_t)(NN * D / 2) * 4;
    unsigned* Wb   = (unsigned*)p;  p += (size_t)(64 * 128 / 2) * 4;
    unsigned* gidx = (unsigned*)p;  p += (size_t)K1BLK * NSB * 4;
    uint2* gsegB   = (uint2*)p;     // K1BLK * REG * 8 = 6,422,528 bytes

    k_bucket<<<K1BLK, 512, 0, stream>>>(dst, src, w, h, W, hb, Wb,
                                        gidx, gsegB);

    k_fused <<<K2BLK, 256, 0, stream>>>(hb, gidx, gsegB, Wb, b, out);
}